// Round 4
// baseline (385.854 us; speedup 1.0000x reference)
//
#include <hip/hip_runtime.h>
#include <hip/hip_bf16.h>

#define DEV __device__ __forceinline__

typedef __attribute__((ext_vector_type(8))) short bf16x8;
typedef __attribute__((ext_vector_type(4))) float f32x4;

// Problem constants
#define BB 4
#define SS 2048
#define DD 1024
#define HH 16
#define HDD 64
#define MM (BB * SS)   // 8192
#define NT (SS / 64)   // 32 q-tiles per (b,h)

DEV short f2bf(float f) {
  unsigned u = __builtin_bit_cast(unsigned, f);
  u = u + 0x7fffu + ((u >> 16) & 1u);
  return (short)(u >> 16);
}

DEV float fexp2(float x) {  // raw v_exp_f32 (2^x), no libm guard code
  float r;
  asm("v_exp_f32 %0, %1" : "=v"(r) : "v"(x));
  return r;
}
DEV float frcp(float x) {
  float r;
  asm("v_rcp_f32 %0, %1" : "=v"(r) : "v"(x));
  return r;
}

DEV void gload_lds16(const void* g, void* l) {
  __builtin_amdgcn_global_load_lds((const __attribute__((address_space(1))) void*)g,
                                   (__attribute__((address_space(3))) void*)l, 16, 0, 0);
}

DEV float redmax16(float v) {
  v = fmaxf(v, __shfl_xor(v, 1));
  v = fmaxf(v, __shfl_xor(v, 2));
  v = fmaxf(v, __shfl_xor(v, 4));
  v = fmaxf(v, __shfl_xor(v, 8));
  return v;
}
DEV float redsum16(float v) {
  v += __shfl_xor(v, 1);
  v += __shfl_xor(v, 2);
  v += __shfl_xor(v, 4);
  v += __shfl_xor(v, 8);
  return v;
}

__global__ __launch_bounds__(256)
void cast_f32_bf16(const float* __restrict__ in, unsigned long long* __restrict__ out, int n4) {
  int i = blockIdx.x * 256 + threadIdx.x;
  const int st = gridDim.x * 256;
  for (; i < n4; i += st) {
    const float4 f = ((const float4*)in)[i];
    unsigned long long a = (unsigned long long)(unsigned short)f2bf(f.x)
        | ((unsigned long long)(unsigned short)f2bf(f.y) << 16)
        | ((unsigned long long)(unsigned short)f2bf(f.z) << 32)
        | ((unsigned long long)(unsigned short)f2bf(f.w) << 48);
    out[i] = a;
  }
}

// C = A[M,K] * Bw[N,K]^T + bias.  EPI=0: scatter to Q/K/V bf16 ws. EPI=1: f32 out.
// Q is pre-scaled by (1/sqrt(HD))*log2(e) so attention softmax runs in exp2 domain.
template<int EPI>
__global__ __launch_bounds__(256)
void gemm_bt(const short* __restrict__ A, const short* __restrict__ Bw,
             const float* __restrict__ bias,
             short* __restrict__ qo, short* __restrict__ ko, short* __restrict__ vo,
             float* __restrict__ co,
             int M, int N, int K) {
  __shared__ short sA[128 * 64];
  __shared__ short sB[128 * 64];
  const int lane = threadIdx.x & 63;
  const int wv = threadIdx.x >> 6;
  const int wm = wv >> 1, wn = wv & 1;
  const int m0 = blockIdx.y * 128;
  const int n0 = blockIdx.x * 128;
  f32x4 acc[4][4] = {};
  const int nkt = K >> 6;
  for (int kt = 0; kt < nkt; ++kt) {
    const int k0 = kt << 6;
    if (kt) __syncthreads();
#pragma unroll
    for (int i = 0; i < 4; ++i) {
      const int c = i * 4 + wv;
      const int b = c * 1024 + lane * 16;
      const int row = b >> 7;
      const int colb = b & 127;
      gload_lds16((const char*)A + ((size_t)(m0 + row) * K + k0) * 2 + colb,
                  (char*)sA + c * 1024);
      gload_lds16((const char*)Bw + ((size_t)(n0 + row) * K + k0) * 2 + colb,
                  (char*)sB + c * 1024);
    }
    __syncthreads();
#pragma unroll
    for (int ks = 0; ks < 2; ++ks) {
      bf16x8 af[4], bf_[4];
#pragma unroll
      for (int i = 0; i < 4; ++i) {
        af[i]  = *(const bf16x8*)&sA[(wm * 64 + i * 16 + (lane & 15)) * 64 + ks * 32 + (lane >> 4) * 8];
        bf_[i] = *(const bf16x8*)&sB[(wn * 64 + i * 16 + (lane & 15)) * 64 + ks * 32 + (lane >> 4) * 8];
      }
#pragma unroll
      for (int i = 0; i < 4; ++i)
#pragma unroll
        for (int j = 0; j < 4; ++j)
          acc[i][j] = __builtin_amdgcn_mfma_f32_16x16x32_bf16(af[i], bf_[j], acc[i][j], 0, 0, 0);
    }
  }
#pragma unroll
  for (int i = 0; i < 4; ++i) {
#pragma unroll
    for (int j = 0; j < 4; ++j) {
#pragma unroll
      for (int r = 0; r < 4; ++r) {
        const int row = m0 + wm * 64 + i * 16 + (lane >> 4) * 4 + r;
        const int col = n0 + wn * 64 + j * 16 + (lane & 15);
        float v = acc[i][j][r] + bias[col];
        if (EPI == 0) {
          const int part = col >> 10, oo = col & 1023;
          const int h = oo >> 6, d = oo & 63;
          const int bb = row >> 11, s = row & 2047;
          if (part == 0)
            qo[(((size_t)bb * HH + h) * SS + s) * HDD + d] = f2bf(v * 0.18033688f); // 0.125*log2(e)
          else if (part == 1)
            ko[(((size_t)bb * HH + h) * SS + s) * HDD + d] = f2bf(v);
          else
            vo[(((size_t)bb * HH + h) * HDD + d) * SS + s] = f2bf(v);
        } else {
          co[(size_t)row * N + col] = v;
        }
      }
    }
  }
}

// Flash attention v4: grid (NT, B*H), 256 threads (4 waves x 16 q-rows).
// qb = NT-1-blockIdx.x (longest blocks dispatch first -> tail packing).
// Q pre-scaled by log2(e)/sqrt(HD); softmax in exp2 domain (raw v_exp_f32).
// K double-buffered in LDS (global_load_lds, XOR-swizzled source / swizzled read).
// V read direct global->reg, issued right after the barrier so its L2 latency
// hides under QK^T + softmax (T14). Defer-max (T13): skip rescale when the
// tile max doesn't beat running max by >8*log2e. Only in-loop barrier: 1/tile.
__global__ __launch_bounds__(256)
void attn_fwd(const short* __restrict__ Q, const short* __restrict__ K,
              const short* __restrict__ V, short* __restrict__ Y) {
  __shared__ short sK[2][64 * 64];
  __shared__ short sP[64][72];
  const int bh = blockIdx.y;
  const int qb = NT - 1 - blockIdx.x;
  const int tid = threadIdx.x, lane = tid & 63, w = tid >> 6;
  const size_t bqk = (size_t)bh * (SS * HDD);
  const size_t bv  = (size_t)bh * (HDD * SS);
  const int b = bh >> 4, h = bh & 15;
  const int lr = lane & 15;        // fragment row/col index
  const int lg = lane >> 4;        // k-group
  const int q0 = qb * 64;

  // K staging geometry: element e (0..511), 16B each; LDS dest linear,
  // global source slot pre-swizzled s = (e&7)^(row&7)  (rule #21 both-sides)
  const int e0 = w * 64 + lane;
  const int e1 = 256 + e0;
  const int r0 = e0 >> 3, s0 = ((e0 & 7) ^ (r0 & 7)) * 8;
  const int r1 = e1 >> 3, s1 = ((e1 & 7) ^ (r1 & 7)) * 8;

  // prologue: stage K tile 0 into buffer 0
  gload_lds16(K + bqk + (size_t)r0 * HDD + s0, &sK[0][e0 * 8]);
  gload_lds16(K + bqk + (size_t)r1 * HDD + s1, &sK[0][e1 * 8]);

  bf16x8 qf[2];
#pragma unroll
  for (int ks = 0; ks < 2; ++ks)
    qf[ks] = *(const bf16x8*)&Q[bqk + (size_t)(q0 + w * 16 + lr) * HDD + ks * 32 + lg * 8];

  f32x4 accO[4] = {};
  float m_[4], l_[4];
#pragma unroll
  for (int r = 0; r < 4; ++r) { m_[r] = -1e30f; l_[r] = 0.f; }

  int cur = 0;
  for (int kt = 0; kt <= qb; ++kt) {
    const int kc0 = kt * 64;
    __syncthreads();   // staged K tile ready; prev tile's LDS reads done
    if (kt < qb) {     // stage next K tile into the other buffer
      const short* gK = K + bqk + (size_t)(kc0 + 64) * 64;
      gload_lds16(gK + (size_t)r0 * HDD + s0, &sK[cur ^ 1][e0 * 8]);
      gload_lds16(gK + (size_t)r1 * HDD + s1, &sK[cur ^ 1][e1 * 8]);
    }

    // V prefetch into registers (independent of P; latency hides under
    // QK^T + softmax). V layout [BH, HD, S] -> contiguous in k.
    bf16x8 vf[2][4];
#pragma unroll
    for (int ks = 0; ks < 2; ++ks)
#pragma unroll
      for (int df = 0; df < 4; ++df)
        vf[ks][df] = *(const bf16x8*)&V[bv + (size_t)(df * 16 + lr) * SS + kc0 + ks * 32 + lg * 8];

    f32x4 sc_[4] = {};
#pragma unroll
    for (int ks = 0; ks < 2; ++ks) {
#pragma unroll
      for (int nf = 0; nf < 4; ++nf) {
        const int row = nf * 16 + lr;
        const bf16x8 kf = *(const bf16x8*)&sK[cur][row * 64 + (((ks << 2) + lg) ^ (lr & 7)) * 8];
        sc_[nf] = __builtin_amdgcn_mfma_f32_16x16x32_bf16(qf[ks], kf, sc_[nf], 0, 0, 0);
      }
    }
    if (kt == qb) {   // diagonal tile: causal mask
#pragma unroll
      for (int nf = 0; nf < 4; ++nf)
#pragma unroll
        for (int r = 0; r < 4; ++r) {
          const int col = kc0 + nf * 16 + lr;
          const int row = q0 + w * 16 + lg * 4 + r;
          if (col > row) sc_[nf][r] = -1e30f;
        }
    }

    // row max of this tile; defer-max: only rescale when it beats m_ by >8*log2e
    float rmv[4];
    bool need = false;
#pragma unroll
    for (int r = 0; r < 4; ++r) {
      float rm = fmaxf(fmaxf(sc_[0][r], sc_[1][r]), fmaxf(sc_[2][r], sc_[3][r]));
      rm = redmax16(rm);
      rmv[r] = rm;
      need = need || (rm > m_[r] + 11.5416f);
    }
    if (__any(need)) {
#pragma unroll
      for (int r = 0; r < 4; ++r) {
        const float mn = fmaxf(m_[r], rmv[r]);
        const float scale = fexp2(m_[r] - mn);
        m_[r] = mn;
        l_[r] *= scale;
#pragma unroll
        for (int df = 0; df < 4; ++df) accO[df][r] *= scale;
      }
    }
#pragma unroll
    for (int r = 0; r < 4; ++r) {
      float rs = 0.f;
#pragma unroll
      for (int nf = 0; nf < 4; ++nf) {
        const float p = fexp2(sc_[nf][r] - m_[r]);
        sc_[nf][r] = p;
        rs += p;
      }
      l_[r] += redsum16(rs);
    }

    // P round-trip through wave-private padded LDS rows (re-fragment for PV)
#pragma unroll
    for (int nf = 0; nf < 4; ++nf)
#pragma unroll
      for (int r = 0; r < 4; ++r)
        sP[w * 16 + lg * 4 + r][nf * 16 + lr] = f2bf(sc_[nf][r]);
#pragma unroll
    for (int ks = 0; ks < 2; ++ks) {
      const bf16x8 pf = *(const bf16x8*)&sP[w * 16 + lr][ks * 32 + lg * 8];
#pragma unroll
      for (int df = 0; df < 4; ++df)
        accO[df] = __builtin_amdgcn_mfma_f32_16x16x32_bf16(pf, vf[ks][df], accO[df], 0, 0, 0);
    }
    cur ^= 1;
  }

#pragma unroll
  for (int r = 0; r < 4; ++r) {
    const float inv = frcp(l_[r]);
    const int srow = q0 + w * 16 + lg * 4 + r;
#pragma unroll
    for (int df = 0; df < 4; ++df) {
      const int dcol = h * HDD + df * 16 + lr;
      Y[((size_t)b * SS + srow) * DD + dcol] = f2bf(accO[df][r] * inv);
    }
  }
}

extern "C" void kernel_launch(void* const* d_in, const int* in_sizes, int n_in,
                              void* d_out, int out_size, void* d_ws, size_t ws_size,
                              hipStream_t stream) {
  const float* x     = (const float*)d_in[0];
  const float* w_qkv = (const float*)d_in[1];
  const float* b_qkv = (const float*)d_in[2];
  const float* w_out = (const float*)d_in[3];
  const float* b_out = (const float*)d_in[4];
  float* out = (float*)d_out;

  const size_t nx = (size_t)MM * DD;        // 8388608
  const size_t nwq = (size_t)3 * DD * DD;   // 3145728
  const size_t nwo = (size_t)DD * DD;       // 1048576

  short* x_bf    = (short*)d_ws;
  short* wqkv_bf = x_bf + nx;
  short* wout_bf = wqkv_bf + nwq;
  short* q_ws    = wout_bf + nwo;
  short* k_ws    = q_ws + nx;
  short* v_ws    = k_ws + nx;
  short* y_ws    = v_ws + nx;

  cast_f32_bf16<<<dim3(2048), dim3(256), 0, stream>>>(x, (unsigned long long*)x_bf, (int)(nx / 4));
  cast_f32_bf16<<<dim3(1024), dim3(256), 0, stream>>>(w_qkv, (unsigned long long*)wqkv_bf, (int)(nwq / 4));
  cast_f32_bf16<<<dim3(512), dim3(256), 0, stream>>>(w_out, (unsigned long long*)wout_bf, (int)(nwo / 4));

  gemm_bt<0><<<dim3(3 * DD / 128, MM / 128), dim3(256), 0, stream>>>(
      x_bf, wqkv_bf, b_qkv, q_ws, k_ws, v_ws, nullptr, MM, 3 * DD, DD);

  attn_fwd<<<dim3(NT, BB * HH), dim3(256), 0, stream>>>(q_ws, k_ws, v_ws, y_ws);

  gemm_bt<1><<<dim3(DD / 128, MM / 128), dim3(256), 0, stream>>>(
      y_ws, wout_bf, b_out, nullptr, nullptr, nullptr, out, MM, DD, DD);
}

// Round 5
// 236.171 us; speedup vs baseline: 1.6338x; 1.6338x over previous
//
#include <hip/hip_runtime.h>
#include <hip/hip_bf16.h>

#define DEV __device__ __forceinline__

typedef __attribute__((ext_vector_type(8))) short bf16x8;
typedef __attribute__((ext_vector_type(4))) float f32x4;

// Problem constants
#define BB 4
#define SS 2048
#define DD 1024
#define HH 16
#define HDD 64
#define MM (BB * SS)   // 8192
#define NT (SS / 64)   // 32 q-tiles per (b,h)

DEV short f2bf(float f) {
  unsigned u = __builtin_bit_cast(unsigned, f);
  u = u + 0x7fffu + ((u >> 16) & 1u);
  return (short)(u >> 16);
}

DEV float fexp2(float x) {  // raw v_exp_f32 (2^x)
  float r;
  asm("v_exp_f32 %0, %1" : "=v"(r) : "v"(x));
  return r;
}
DEV float frcp(float x) {
  float r;
  asm("v_rcp_f32 %0, %1" : "=v"(r) : "v"(x));
  return r;
}

DEV void gload_lds16(const void* g, void* l) {
  __builtin_amdgcn_global_load_lds((const __attribute__((address_space(1))) void*)g,
                                   (__attribute__((address_space(3))) void*)l, 16, 0, 0);
}

// DPP 16-lane reductions (VALU pipe; avoids ds_swizzle dependent-latency chains)
// quad_perm(1,0,3,2)=0xB1 (xor1), quad_perm(2,3,0,1)=0x4E (xor2),
// row_half_mirror=0x141 (xor-ish 4), row_mirror=0x140 (xor-ish 8)
template<int CTRL> DEV float dpp_maxstep(float v) {
  int s = __builtin_amdgcn_update_dpp(0, __builtin_bit_cast(int, v), CTRL, 0xF, 0xF, true);
  return fmaxf(v, __builtin_bit_cast(float, s));
}
template<int CTRL> DEV float dpp_addstep(float v) {
  int s = __builtin_amdgcn_update_dpp(0, __builtin_bit_cast(int, v), CTRL, 0xF, 0xF, true);
  return v + __builtin_bit_cast(float, s);
}
DEV float redmax16(float v) {
  v = dpp_maxstep<0xB1>(v);
  v = dpp_maxstep<0x4E>(v);
  v = dpp_maxstep<0x141>(v);
  v = dpp_maxstep<0x140>(v);
  return v;
}
DEV float redsum16(float v) {
  v = dpp_addstep<0xB1>(v);
  v = dpp_addstep<0x4E>(v);
  v = dpp_addstep<0x141>(v);
  v = dpp_addstep<0x140>(v);
  return v;
}

__global__ __launch_bounds__(256)
void cast_f32_bf16(const float* __restrict__ in, unsigned long long* __restrict__ out, int n4) {
  int i = blockIdx.x * 256 + threadIdx.x;
  const int st = gridDim.x * 256;
  for (; i < n4; i += st) {
    const float4 f = ((const float4*)in)[i];
    unsigned long long a = (unsigned long long)(unsigned short)f2bf(f.x)
        | ((unsigned long long)(unsigned short)f2bf(f.y) << 16)
        | ((unsigned long long)(unsigned short)f2bf(f.z) << 32)
        | ((unsigned long long)(unsigned short)f2bf(f.w) << 48);
    out[i] = a;
  }
}

// C = A[M,K] * Bw[N,K]^T + bias.  EPI=0: scatter to Q/K/V bf16 ws. EPI=1: f32 out.
// Q pre-scaled by (1/sqrt(HD))*log2(e): attention softmax runs in exp2 domain.
template<int EPI>
__global__ __launch_bounds__(256)
void gemm_bt(const short* __restrict__ A, const short* __restrict__ Bw,
             const float* __restrict__ bias,
             short* __restrict__ qo, short* __restrict__ ko, short* __restrict__ vo,
             float* __restrict__ co,
             int M, int N, int K) {
  __shared__ short sA[128 * 64];
  __shared__ short sB[128 * 64];
  const int lane = threadIdx.x & 63;
  const int wv = threadIdx.x >> 6;
  const int wm = wv >> 1, wn = wv & 1;
  const int m0 = blockIdx.y * 128;
  const int n0 = blockIdx.x * 128;
  f32x4 acc[4][4] = {};
  const int nkt = K >> 6;
  for (int kt = 0; kt < nkt; ++kt) {
    const int k0 = kt << 6;
    if (kt) __syncthreads();
#pragma unroll
    for (int i = 0; i < 4; ++i) {
      const int c = i * 4 + wv;
      const int b = c * 1024 + lane * 16;
      const int row = b >> 7;
      const int colb = b & 127;
      gload_lds16((const char*)A + ((size_t)(m0 + row) * K + k0) * 2 + colb,
                  (char*)sA + c * 1024);
      gload_lds16((const char*)Bw + ((size_t)(n0 + row) * K + k0) * 2 + colb,
                  (char*)sB + c * 1024);
    }
    __syncthreads();
#pragma unroll
    for (int ks = 0; ks < 2; ++ks) {
      bf16x8 af[4], bf_[4];
#pragma unroll
      for (int i = 0; i < 4; ++i) {
        af[i]  = *(const bf16x8*)&sA[(wm * 64 + i * 16 + (lane & 15)) * 64 + ks * 32 + (lane >> 4) * 8];
        bf_[i] = *(const bf16x8*)&sB[(wn * 64 + i * 16 + (lane & 15)) * 64 + ks * 32 + (lane >> 4) * 8];
      }
#pragma unroll
      for (int i = 0; i < 4; ++i)
#pragma unroll
        for (int j = 0; j < 4; ++j)
          acc[i][j] = __builtin_amdgcn_mfma_f32_16x16x32_bf16(af[i], bf_[j], acc[i][j], 0, 0, 0);
    }
  }
#pragma unroll
  for (int i = 0; i < 4; ++i) {
#pragma unroll
    for (int j = 0; j < 4; ++j) {
#pragma unroll
      for (int r = 0; r < 4; ++r) {
        const int row = m0 + wm * 64 + i * 16 + (lane >> 4) * 4 + r;
        const int col = n0 + wn * 64 + j * 16 + (lane & 15);
        float v = acc[i][j][r] + bias[col];
        if (EPI == 0) {
          const int part = col >> 10, oo = col & 1023;
          const int h = oo >> 6, d = oo & 63;
          const int bb = row >> 11, s = row & 2047;
          if (part == 0)
            qo[(((size_t)bb * HH + h) * SS + s) * HDD + d] = f2bf(v * 0.18033688f); // 0.125*log2(e)
          else if (part == 1)
            ko[(((size_t)bb * HH + h) * SS + s) * HDD + d] = f2bf(v);
          else
            vo[(((size_t)bb * HH + h) * HDD + d) * SS + s] = f2bf(v);
        } else {
          co[(size_t)row * N + col] = v;
        }
      }
    }
  }
}

// Flash attention v5 (= v3 structure + VALU trims):
// grid (NT/2, B*H), 256 threads (4 waves x 16 q-rows); paired q-tiles
// {bx, NT-1-bx} -> 33 tiles/block uniform. K/V double-buffered in LDS via
// global_load_lds (XOR-swizzled source / swizzled read, rule #21). Softmax in
// exp2 domain with DPP reductions (VALU pipe, no ds_swizzle chains), defer-max
// (T13, THR=8*log2e), v_rcp epilogue. One barrier per tile.
__global__ __launch_bounds__(256)
void attn_fwd(const short* __restrict__ Q, const short* __restrict__ K,
              const short* __restrict__ V, short* __restrict__ Y) {
  __shared__ short sK[2][64 * 64];
  __shared__ short sV[2][64 * 64];
  __shared__ short sP[64][72];
  const int bh = blockIdx.y;
  const int tid = threadIdx.x, lane = tid & 63, w = tid >> 6;
  const size_t bqk = (size_t)bh * (SS * HDD);
  const size_t bv  = (size_t)bh * (HDD * SS);
  const int b = bh >> 4, h = bh & 15;
  const int lr = lane & 15;        // fragment row/col index
  const int lg = lane >> 4;        // k-group

  // staging geometry: element e (0..511), 16B each; LDS dest linear,
  // global source slot pre-swizzled s = (e&7)^(row&7)
  const int e0 = w * 64 + lane;
  const int e1 = 256 + e0;
  const int r0 = e0 >> 3, s0 = ((e0 & 7) ^ (r0 & 7)) * 8;
  const int r1 = e1 >> 3, s1 = ((e1 & 7) ^ (r1 & 7)) * 8;

  for (int qsel = 0; qsel < 2; ++qsel) {
    const int qb = qsel ? (NT - 1 - blockIdx.x) : blockIdx.x;
    const int q0 = qb * 64;

    __syncthreads();   // protect buffer re-stage vs previous q-tile's reads

    // prologue: stage tile 0 into buffer 0
    {
      const short* gK = K + bqk;
      const short* gV = V + bv;
      gload_lds16(gK + (size_t)r0 * HDD + s0, &sK[0][e0 * 8]);
      gload_lds16(gV + (size_t)r0 * SS + s0, &sV[0][e0 * 8]);
      gload_lds16(gK + (size_t)r1 * HDD + s1, &sK[0][e1 * 8]);
      gload_lds16(gV + (size_t)r1 * SS + s1, &sV[0][e1 * 8]);
    }

    bf16x8 qf[2];
#pragma unroll
    for (int ks = 0; ks < 2; ++ks)
      qf[ks] = *(const bf16x8*)&Q[bqk + (size_t)(q0 + w * 16 + lr) * HDD + ks * 32 + lg * 8];

    f32x4 accO[4] = {};
    float m_[4], l_[4];
#pragma unroll
    for (int r = 0; r < 4; ++r) { m_[r] = -1e30f; l_[r] = 0.f; }

    int cur = 0;
    for (int kt = 0; kt <= qb; ++kt) {
      const int kc0 = kt * 64;
      __syncthreads();   // staged tile ready (vmcnt drained); prev reads done
      if (kt < qb) {     // stage next tile into the other buffer
        const short* gK = K + bqk + (size_t)(kc0 + 64) * 64;
        const short* gV = V + bv + kc0 + 64;
        gload_lds16(gK + (size_t)r0 * HDD + s0, &sK[cur ^ 1][e0 * 8]);
        gload_lds16(gV + (size_t)r0 * SS + s0, &sV[cur ^ 1][e0 * 8]);
        gload_lds16(gK + (size_t)r1 * HDD + s1, &sK[cur ^ 1][e1 * 8]);
        gload_lds16(gV + (size_t)r1 * SS + s1, &sV[cur ^ 1][e1 * 8]);
      }

      f32x4 sc_[4] = {};
#pragma unroll
      for (int ks = 0; ks < 2; ++ks) {
#pragma unroll
        for (int nf = 0; nf < 4; ++nf) {
          const int row = nf * 16 + lr;
          const bf16x8 kf = *(const bf16x8*)&sK[cur][row * 64 + (((ks << 2) + lg) ^ (lr & 7)) * 8];
          sc_[nf] = __builtin_amdgcn_mfma_f32_16x16x32_bf16(qf[ks], kf, sc_[nf], 0, 0, 0);
        }
      }
      if (kt == qb) {   // diagonal tile: causal mask
#pragma unroll
        for (int nf = 0; nf < 4; ++nf)
#pragma unroll
          for (int r = 0; r < 4; ++r) {
            const int col = kc0 + nf * 16 + lr;
            const int row = q0 + w * 16 + lg * 4 + r;
            if (col > row) sc_[nf][r] = -1e30f;
          }
      }

      // tile row-max (DPP); defer-max: rescale only if it beats m_ by >8*log2e
      float rmv[4];
      bool need = false;
#pragma unroll
      for (int r = 0; r < 4; ++r) {
        float rm = fmaxf(fmaxf(sc_[0][r], sc_[1][r]), fmaxf(sc_[2][r], sc_[3][r]));
        rm = redmax16(rm);
        rmv[r] = rm;
        need = need || (rm > m_[r] + 11.5416f);
      }
      if (__any(need)) {
#pragma unroll
        for (int r = 0; r < 4; ++r) {
          const float mn = fmaxf(m_[r], rmv[r]);
          const float scale = fexp2(m_[r] - mn);
          m_[r] = mn;
          l_[r] *= scale;
#pragma unroll
          for (int df = 0; df < 4; ++df) accO[df][r] *= scale;
        }
      }
#pragma unroll
      for (int r = 0; r < 4; ++r) {
        float rs = 0.f;
#pragma unroll
        for (int nf = 0; nf < 4; ++nf) {
          const float p = fexp2(sc_[nf][r] - m_[r]);
          sc_[nf][r] = p;
          rs += p;
        }
        l_[r] += redsum16(rs);
      }

      // P round-trip through wave-private padded LDS rows (re-fragment for PV)
#pragma unroll
      for (int nf = 0; nf < 4; ++nf)
#pragma unroll
        for (int r = 0; r < 4; ++r)
          sP[w * 16 + lg * 4 + r][nf * 16 + lr] = f2bf(sc_[nf][r]);
#pragma unroll
      for (int ks = 0; ks < 2; ++ks) {
        const bf16x8 pf = *(const bf16x8*)&sP[w * 16 + lr][ks * 32 + lg * 8];
#pragma unroll
        for (int df = 0; df < 4; ++df) {
          const int row = df * 16 + lr;
          const bf16x8 vf = *(const bf16x8*)&sV[cur][row * 64 + (((ks << 2) + lg) ^ (lr & 7)) * 8];
          accO[df] = __builtin_amdgcn_mfma_f32_16x16x32_bf16(pf, vf, accO[df], 0, 0, 0);
        }
      }
      cur ^= 1;
    }
#pragma unroll
    for (int r = 0; r < 4; ++r) {
      const float inv = frcp(l_[r]);
      const int srow = q0 + w * 16 + lg * 4 + r;
#pragma unroll
      for (int df = 0; df < 4; ++df) {
        const int dcol = h * HDD + df * 16 + lr;
        Y[((size_t)b * SS + srow) * DD + dcol] = f2bf(accO[df][r] * inv);
      }
    }
  }
}

extern "C" void kernel_launch(void* const* d_in, const int* in_sizes, int n_in,
                              void* d_out, int out_size, void* d_ws, size_t ws_size,
                              hipStream_t stream) {
  const float* x     = (const float*)d_in[0];
  const float* w_qkv = (const float*)d_in[1];
  const float* b_qkv = (const float*)d_in[2];
  const float* w_out = (const float*)d_in[3];
  const float* b_out = (const float*)d_in[4];
  float* out = (float*)d_out;

  const size_t nx = (size_t)MM * DD;        // 8388608
  const size_t nwq = (size_t)3 * DD * DD;   // 3145728
  const size_t nwo = (size_t)DD * DD;       // 1048576

  short* x_bf    = (short*)d_ws;
  short* wqkv_bf = x_bf + nx;
  short* wout_bf = wqkv_bf + nwq;
  short* q_ws    = wout_bf + nwo;
  short* k_ws    = q_ws + nx;
  short* v_ws    = k_ws + nx;
  short* y_ws    = v_ws + nx;

  cast_f32_bf16<<<dim3(2048), dim3(256), 0, stream>>>(x, (unsigned long long*)x_bf, (int)(nx / 4));
  cast_f32_bf16<<<dim3(1024), dim3(256), 0, stream>>>(w_qkv, (unsigned long long*)wqkv_bf, (int)(nwq / 4));
  cast_f32_bf16<<<dim3(512), dim3(256), 0, stream>>>(w_out, (unsigned long long*)wout_bf, (int)(nwo / 4));

  gemm_bt<0><<<dim3(3 * DD / 128, MM / 128), dim3(256), 0, stream>>>(
      x_bf, wqkv_bf, b_qkv, q_ws, k_ws, v_ws, nullptr, MM, 3 * DD, DD);

  attn_fwd<<<dim3(NT / 2, BB * HH), dim3(256), 0, stream>>>(q_ws, k_ws, v_ws, y_ws);

  gemm_bt<1><<<dim3(DD / 128, MM / 128), dim3(256), 0, stream>>>(
      y_ws, wout_bf, b_out, nullptr, nullptr, nullptr, out, MM, DD, DD);
}